// Round 5
// baseline (112.774 us; speedup 1.0000x reference)
//
#include <hip/hip_runtime.h>
#include <math.h>
#include <limits.h>

#define D 128
#define NSUBJ 16
#define MAXN 640        // bucket stride; groups ~512 +- 22 (~6 sigma safety)
#define MARGIN 0.8f
#define PRB 32          // rows per prep block
#define NPB 256         // prep blocks = 8192 / PRB
#define TI 16           // i-rows per triplet block (one MFMA row-tile)
#define TJ 64           // j-cols per tile (4 waves x 16)
#define NSTRIPE 32      // stripes per subject
#define NSPLIT 2        // j-range halves (TLP x2: 1024 blocks = 4/CU, 16 waves/CU)
#define NBLK (NSUBJ * NSTRIPE * NSPLIT)   // 1024 blocks
#define HROWS (NSUBJ * MAXN)              // 10240 row slots per half

typedef __attribute__((ext_vector_type(8))) short bf16x8;
typedef __attribute__((ext_vector_type(4))) float f32x4;

static __device__ __forceinline__ short f2bf(float f) {
    union { float f; unsigned u; } v; v.f = f;
    unsigned r = v.u + 0x7FFF + ((v.u >> 16) & 1);   // RNE
    return (short)(r >> 16);
}

// ---------------------------------------------------------------------------
// P1: per-block subject histogram (LDS atomics only).
// ---------------------------------------------------------------------------
__global__ __launch_bounds__(64) void hist_kernel(const int* __restrict__ sbj,
                                                  int* __restrict__ hist) {
    __shared__ int s_cnt[NSUBJ];
    const int t = threadIdx.x, bid = blockIdx.x;
    if (t < NSUBJ) s_cnt[t] = 0;
    __syncthreads();
    if (t < PRB) atomicAdd(&s_cnt[sbj[bid * PRB + t]], 1);
    __syncthreads();
    if (t < NSUBJ) hist[bid * NSUBJ + t] = s_cnt[t];
}

// ---------------------------------------------------------------------------
// P2: scan fused into prep — each block computes its own exclusive base by
// summing hist[0..bid) (<=16KB of L2-hit reads, parallel across blocks).
// Slot = base + LDS-atomic rank. Block NPB-1 writes counts[s].
// Bucket ORDER doesn't matter: all selects tie-break on the ORIGINAL index.
// ---------------------------------------------------------------------------
__global__ __launch_bounds__(256) void prep_kernel(
        const float* __restrict__ emb, const int* __restrict__ labels,
        const int* __restrict__ sbj, const int* __restrict__ hist,
        int* __restrict__ counts,
        int4* __restrict__ pmeta, short* __restrict__ ebf, int B) {
    __shared__ int s_cnt[NSUBJ], s_base[NSUBJ], s_slot[PRB];
    const int t = threadIdx.x, bid = blockIdx.x;
    if (t < NSUBJ) { s_cnt[t] = 0; s_base[t] = 0; }
    __syncthreads();
    // exclusive scan over preceding blocks: thread t covers subject t&15,
    // block segment [(t>>4)*16, +16) clipped to [0, bid)
    {
        const int ss = t & 15, seg0 = (t >> 4) * 16;
        int part = 0;
        const int hi = min(bid, seg0 + 16);
        for (int b = seg0; b < hi; ++b) part += hist[b * NSUBJ + ss];
        if (part) atomicAdd(&s_base[ss], part);
    }
    int s = 0, mypos = 0;
    if (t < PRB) { s = sbj[bid * PRB + t]; mypos = atomicAdd(&s_cnt[s], 1); }
    __syncthreads();
    if (t < PRB) {
        int pos = s_base[s] + mypos;
        s_slot[t] = (pos < MAXN) ? (s * MAXN + pos) : -1;   // never fires at 6 sigma
    }
    if (bid == NPB - 1 && t < NSUBJ)
        counts[t] = s_base[t] + s_cnt[t];                   // totals for triplet
    __syncthreads();
#pragma unroll
    for (int it = 0; it < (PRB * 16) / 256; ++it) {         // 2 iters: 16 rows x 16 thr
        int lin = it * 256 + t;
        int row = lin >> 4, u = lin & 15;
        int i = bid * PRB + row;
        int slot = s_slot[row];
        const float4* rp = (const float4*)(emb + (size_t)i * D);
        float4 a0 = rp[u * 2], a1 = rp[u * 2 + 1];
        float ssq = 0.f;
        ssq = fmaf(a0.x, a0.x, ssq); ssq = fmaf(a0.y, a0.y, ssq);
        ssq = fmaf(a0.z, a0.z, ssq); ssq = fmaf(a0.w, a0.w, ssq);
        ssq = fmaf(a1.x, a1.x, ssq); ssq = fmaf(a1.y, a1.y, ssq);
        ssq = fmaf(a1.z, a1.z, ssq); ssq = fmaf(a1.w, a1.w, ssq);
#pragma unroll
        for (int off = 8; off > 0; off >>= 1) ssq += __shfl_down(ssq, off, 16);
        // lane u==0 of each 16-group holds the total; no broadcast needed
        if (slot >= 0) {
            bf16x8 pk;
            pk[0] = f2bf(a0.x); pk[1] = f2bf(a0.y); pk[2] = f2bf(a0.z); pk[3] = f2bf(a0.w);
            pk[4] = f2bf(a1.x); pk[5] = f2bf(a1.y); pk[6] = f2bf(a1.z); pk[7] = f2bf(a1.w);
            *(bf16x8*)&ebf[(size_t)slot * D + u * 8] = pk;
            if (u == 0)
                pmeta[slot] = make_int4(labels[i], i, __float_as_int(ssq), 0);
        }
    }
}

// Load one j-tile's B fragment + column meta into NAMED registers
// (compile-time indices only — dynamic VGPR indexing demotes to scratch).
#define LOADTILE(B0, B1, B2, B3, MI, ML, MS, JT)                         \
    do {                                                                 \
        int jl_ = (JT) * TJ + w * 16 + c, cl_ = min(jl_, n - 1);         \
        const short* rp_ = ebf + (size_t)(base + cl_) * D;               \
        B0 = *(const bf16x8*)&rp_[q * 8];                                \
        B1 = *(const bf16x8*)&rp_[32 + q * 8];                           \
        B2 = *(const bf16x8*)&rp_[64 + q * 8];                           \
        B3 = *(const bf16x8*)&rp_[96 + q * 8];                           \
        int4 m_ = pmeta[base + cl_];                                     \
        MI = (jl_ < n) ? m_.y : -1; ML = m_.x; MS = __int_as_float(m_.z);\
    } while (0)

// Within a lane j is scanned ascending, so strict >/< keeps the smallest
// index on ties. Cross-lane reduces retain explicit tie-breaks.
#define STEP(B0, B1, B2, B3, MI, ML, MS)                                 \
    do {                                                                 \
        f32x4 acc = {0.f, 0.f, 0.f, 0.f};                                \
        acc = __builtin_amdgcn_mfma_f32_16x16x32_bf16(afr[0], B0, acc, 0, 0, 0); \
        acc = __builtin_amdgcn_mfma_f32_16x16x32_bf16(afr[1], B1, acc, 0, 0, 0); \
        acc = __builtin_amdgcn_mfma_f32_16x16x32_bf16(afr[2], B2, acc, 0, 0, 0); \
        acc = __builtin_amdgcn_mfma_f32_16x16x32_bf16(afr[3], B3, acc, 0, 0, 0); \
        if ((MI) >= 0) {                                                 \
            _Pragma("unroll")                                            \
            for (int r = 0; r < 4; ++r) {                                \
                float v = fmaf(-2.f, acc[r], (MS));                      \
                if ((ML) == li[r]) {                                     \
                    if ((MI) != gI[r] && v > vP[r]) { vP[r] = v; iP[r] = (MI); } \
                } else if (v < vN[r]) { vN[r] = v; iN[r] = (MI); }       \
            }                                                            \
        }                                                                \
    } while (0)

// triplet: MFMA Gram + fused hardest-pos/neg selection over HALF the j-tiles.
// J-split x2: 1024 blocks at 4/CU (16 waves/CU TLP, 2x) and half the serial
// VMEM chain per wave (R1 counters: waves resident but 93% memory-stalled;
// ILP depth was neutral -> TLP + shorter chain are the remaining levers).
// Per-row partial {vP,iP,vN,iN} plain-stored to parr[half]; loss in finalize.
__global__ __launch_bounds__(256, 4) void triplet_kernel(
        const short* __restrict__ ebf, const int4* __restrict__ pmeta,
        const int* __restrict__ counts, float4* __restrict__ parr) {
    const int bid = blockIdx.x, t = threadIdx.x;
    const int s = bid & 15;              // both halves of s pin to XCD s%8
    const int stripe = (bid >> 4) & 31;  // 0..31
    const int h = bid >> 9;              // j-half 0/1
    const int base = s * MAXN;
    const int n = min(counts[s], MAXN);
    const int lane = t & 63, w = t >> 6, c = lane & 15, q = lane >> 4;

    __shared__ float svP[TI][4]; __shared__ int siP[TI][4];
    __shared__ float svN[TI][4]; __shared__ int siN[TI][4];

    const int nt  = (n + TJ - 1) / TJ;
    const int nt0 = (nt + 1) >> 1;             // half 0 gets ceil(nt/2)
    const int jt0 = h ? nt0 : 0;
    const int jte = h ? nt : nt0;

    for (int i0 = stripe * TI; i0 < n; i0 += NSTRIPE * TI) {
        const int nrows = min(TI, n - i0);

        bf16x8 afr[4];
        {
            const short* ap = ebf + (size_t)(base + i0 + min(c, nrows - 1)) * D;
#pragma unroll
            for (int st = 0; st < 4; ++st)
                afr[st] = *(const bf16x8*)&ap[st * 32 + q * 8];
        }
        int li[4], gI[4];
#pragma unroll
        for (int r = 0; r < 4; ++r) {
            int row = q * 4 + r;
            if (row < nrows) { int4 m = pmeta[base + i0 + row]; li[r] = m.x; gI[r] = m.y; }
            else             { li[r] = INT_MIN; gI[r] = -1; }
        }

        float vP[4], vN[4]; int iP[4], iN[4];
#pragma unroll
        for (int r = 0; r < 4; ++r) {
            vP[r] = -INFINITY; iP[r] = -1;
            vN[r] =  INFINITY; iN[r] = -1;
        }

        // ---- 2-deep pipeline over this half's tiles (84-VGPR variant:
        // fits 4 blocks/CU; 4-deep at 120 VGPR would cap occupancy) ----
        bf16x8 b00, b01, b02, b03, b10, b11, b12, b13;
        int mi0 = -1, ml0 = INT_MIN, mi1 = -1, ml1 = INT_MIN;
        float ms0 = 0.f, ms1 = 0.f;
        if (jt0 < jte)     LOADTILE(b00, b01, b02, b03, mi0, ml0, ms0, jt0);
        if (jt0 + 1 < jte) LOADTILE(b10, b11, b12, b13, mi1, ml1, ms1, jt0 + 1);

        for (int jt = jt0; jt < jte; jt += 2) {
            {   // even tile: consume buffer 0, refill for jt+2
                bf16x8 c0 = b00, c1 = b01, c2 = b02, c3 = b03;
                int cmi = mi0, cml = ml0; float cms = ms0;
                if (jt + 2 < jte) LOADTILE(b00, b01, b02, b03, mi0, ml0, ms0, jt + 2);
                STEP(c0, c1, c2, c3, cmi, cml, cms);
            }
            if (jt + 1 < jte) {   // odd tile: consume buffer 1, refill for jt+3
                bf16x8 c0 = b10, c1 = b11, c2 = b12, c3 = b13;
                int cmi = mi1, cml = ml1; float cms = ms1;
                if (jt + 3 < jte) LOADTILE(b10, b11, b12, b13, mi1, ml1, ms1, jt + 3);
                STEP(c0, c1, c2, c3, cmi, cml, cms);
            }
        }

        // reduce across the 16 col-lanes (tie-break: smallest original index)
#pragma unroll
        for (int off = 8; off > 0; off >>= 1) {
#pragma unroll
            for (int r = 0; r < 4; ++r) {
                float ov = __shfl_down(vP[r], off, 16);
                int   oi = __shfl_down(iP[r], off, 16);
                if (ov > vP[r] || (ov == vP[r] && (unsigned)oi < (unsigned)iP[r])) {
                    vP[r] = ov; iP[r] = oi;
                }
                float on = __shfl_down(vN[r], off, 16);
                int   oj = __shfl_down(iN[r], off, 16);
                if (on < vN[r] || (on == vN[r] && (unsigned)oj < (unsigned)iN[r])) {
                    vN[r] = on; iN[r] = oj;
                }
            }
        }
        if (c == 0) {
#pragma unroll
            for (int r = 0; r < 4; ++r) {
                int row = q * 4 + r;
                svP[row][w] = vP[r]; siP[row][w] = iP[r];
                svN[row][w] = vN[r]; siN[row][w] = iN[r];
            }
        }
        __syncthreads();

        // per-row combine across waves -> plain store of this half's partial
        if (t < TI) {
            float bp = svP[t][0]; int ip = siP[t][0];
            float bn = svN[t][0]; int in_ = siN[t][0];
#pragma unroll
            for (int ww = 1; ww < 4; ++ww) {
                float o = svP[t][ww]; int oi = siP[t][ww];
                if (o > bp || (o == bp && (unsigned)oi < (unsigned)ip)) { bp = o; ip = oi; }
                float on = svN[t][ww]; int oj = siN[t][ww];
                if (on < bn || (on == bn && (unsigned)oj < (unsigned)in_)) { bn = on; in_ = oj; }
            }
            if (t < nrows) {
                float4 v;
                v.x = bp; v.y = __int_as_float(ip);
                v.z = bn; v.w = __int_as_float(in_);
                parr[(size_t)h * HROWS + base + i0 + t] = v;
            }
        }
        if (i0 + NSTRIPE * TI < n) __syncthreads();   // barrier only if another stripe
    }
}

// finalize: combine the two halves per row, per-row loss, global mean.
// ~500 KB of coalesced L2-resident reads with 1024 threads (~2-4 us).
// Dispatch boundary guarantees visibility of parr.
__global__ __launch_bounds__(1024) void finalize_kernel(
        const float4* __restrict__ parr, const int4* __restrict__ pmeta,
        const int* __restrict__ counts, float* __restrict__ out) {
    __shared__ float fs[16]; __shared__ int fc[16];
    const int t = threadIdx.x;
    float sum = 0.f; int cnt = 0;
    for (int s = 0; s < NSUBJ; ++s) {
        const int ns = min(counts[s], MAXN);
        for (int r = t; r < ns; r += 1024) {
            const int slot = s * MAXN + r;
            float4 a = parr[slot];
            float4 b = parr[HROWS + slot];
            float bp = a.x; int ip = __float_as_int(a.y);
            {
                float o = b.x; int oi = __float_as_int(b.z == b.z ? b.y : b.y); // b.y
                oi = __float_as_int(b.y);
                if (o > bp || (o == bp && (unsigned)oi < (unsigned)ip)) { bp = o; ip = oi; }
            }
            float bn = a.z; int in_ = __float_as_int(a.w);
            {
                float o = b.z; int oi = __float_as_int(b.w);
                if (o < bn || (o == bn && (unsigned)oi < (unsigned)in_)) { bn = o; in_ = oi; }
            }
            if (ip >= 0 && in_ >= 0) {
                float sqi = __int_as_float(pmeta[slot].z);
                float dap = sqrtf(fmaxf(bp + sqi, 0.f));
                float dan = sqrtf(fmaxf(bn + sqi, 0.f));
                sum += fmaxf(dap - dan + MARGIN, 0.f);
                cnt += 1;
            }
        }
    }
#pragma unroll
    for (int off = 32; off > 0; off >>= 1) {
        sum += __shfl_down(sum, off, 64);
        cnt += __shfl_down(cnt, off, 64);
    }
    if ((t & 63) == 0) { fs[t >> 6] = sum; fc[t >> 6] = cnt; }
    __syncthreads();
    if (t < 16) {
        float s2 = fs[t]; int c2 = fc[t];
#pragma unroll
        for (int off = 8; off > 0; off >>= 1) {
            s2 += __shfl_down(s2, off, 16);
            c2 += __shfl_down(c2, off, 16);
        }
        if (t == 0) out[0] = (c2 > 0) ? (s2 / (float)c2) : 0.0f;
    }
}

extern "C" void kernel_launch(void* const* d_in, const int* in_sizes, int n_in,
                              void* d_out, int out_size, void* d_ws, size_t ws_size,
                              hipStream_t stream) {
    const float* emb    = (const float*)d_in[0];
    const int*   labels = (const int*)d_in[1];
    const int*   sbj    = (const int*)d_in[2];
    float*       out    = (float*)d_out;
    int B = in_sizes[1];   // 8192

    // Workspace:
    //   [0,64)      int counts[16]
    //   [256, +NPB*NSUBJ*4)          int hist[NPB][NSUBJ] (16 KB)
    //   [align256, +2*HROWS*16)      float4 parr[2][HROWS] (320 KB)
    //   [align256, +HROWS*16)        int4 pmeta (160 KB)
    //   [align256, +HROWS*D*2)       short ebf (~2.62 MB)
    char*  ws        = (char*)d_ws;
    int*   counts    = (int*)ws;
    int*   hist      = (int*)(ws + 256);
    size_t parr_off  = (256 + (size_t)NPB * NSUBJ * sizeof(int) + 255) & ~(size_t)255;
    float4* parr     = (float4*)(ws + parr_off);
    size_t pmeta_off = (parr_off + 2 * (size_t)HROWS * sizeof(float4) + 255) & ~(size_t)255;
    int4*  pmeta     = (int4*)(ws + pmeta_off);
    size_t ebf_off   = (pmeta_off + (size_t)HROWS * sizeof(int4) + 255) & ~(size_t)255;
    short* ebf       = (short*)(ws + ebf_off);

    hist_kernel<<<B / PRB, 64, 0, stream>>>(sbj, hist);
    prep_kernel<<<B / PRB, 256, 0, stream>>>(emb, labels, sbj, hist, counts,
                                             pmeta, ebf, B);
    triplet_kernel<<<NBLK, 256, 0, stream>>>(ebf, pmeta, counts, parr);
    finalize_kernel<<<1, 1024, 0, stream>>>(parr, pmeta, counts, out);
}

// Round 6
// 102.551 us; speedup vs baseline: 1.0997x; 1.0997x over previous
//
#include <hip/hip_runtime.h>
#include <math.h>
#include <limits.h>

#define D 128
#define NSUBJ 16
#define MAXN 640        // bucket stride; groups ~512 +- 22 (~6 sigma safety)
#define MARGIN 0.8f
#define PRB 32          // rows per prep block
#define NPB 256         // prep blocks = 8192 / PRB
#define TI 16           // i-rows per triplet block (one MFMA row-tile)
#define TJ 64           // j-cols per tile (4 waves x 16)
#define NSTRIPE 32      // stripes per subject
#define NBLK (NSUBJ * NSTRIPE)   // 512 blocks = 2/CU

typedef __attribute__((ext_vector_type(8))) short bf16x8;
typedef __attribute__((ext_vector_type(4))) float f32x4;

static __device__ __forceinline__ short f2bf(float f) {
    union { float f; unsigned u; } v; v.f = f;
    unsigned r = v.u + 0x7FFF + ((v.u >> 16) & 1);   // RNE
    return (short)(r >> 16);
}

// ---------------------------------------------------------------------------
// prep (hist+scan merged): each block computes its own exclusive per-subject
// base DIRECTLY from sbj[0..bid*PRB) via wave-ballot histogram (16 ballots
// per 64 elements; <=32 iters for the last block) — removes the hist kernel
// and one kernel-boundary drain. Slot = base + LDS-atomic rank.
// Bucket ORDER doesn't matter: all selects tie-break on the ORIGINAL index.
// ---------------------------------------------------------------------------
__global__ __launch_bounds__(256) void prep_kernel(
        const float* __restrict__ emb, const int* __restrict__ labels,
        const int* __restrict__ sbj, int* __restrict__ counts,
        int4* __restrict__ pmeta, short* __restrict__ ebf, int B) {
    __shared__ int s_cnt[NSUBJ], s_base[NSUBJ], s_slot[PRB];
    const int t = threadIdx.x, bid = blockIdx.x;
    if (t < NSUBJ) { s_cnt[t] = 0; s_base[t] = 0; }
    __syncthreads();
    const int pre = bid * PRB;           // elements preceding this block
    {   // ballot histogram of sbj[0..pre): wave wv covers j0=wv*64 step 256
        const int wv = t >> 6, lane = t & 63;
        int myCnt = 0;                   // count for subject == lane (lane<16)
        for (int j0 = wv * 64; j0 < pre; j0 += 256) {
            int v = (j0 + lane < pre) ? sbj[j0 + lane] : -1;
#pragma unroll
            for (int s2 = 0; s2 < NSUBJ; ++s2) {
                unsigned long long m = __ballot(v == s2);
                if (lane == s2) myCnt += (int)__popcll(m);
            }
        }
        if (lane < NSUBJ && myCnt) atomicAdd(&s_base[lane], myCnt);
    }
    int s = 0, mypos = 0;
    if (t < PRB) { s = sbj[pre + t]; mypos = atomicAdd(&s_cnt[s], 1); }
    __syncthreads();
    if (t < PRB) {
        int pos = s_base[s] + mypos;
        s_slot[t] = (pos < MAXN) ? (s * MAXN + pos) : -1;   // never fires at 6 sigma
    }
    if (bid == NPB - 1 && t < NSUBJ)
        counts[t] = s_base[t] + s_cnt[t];                   // totals for triplet
    __syncthreads();
#pragma unroll
    for (int it = 0; it < (PRB * 16) / 256; ++it) {         // 2 iters: 16 rows x 16 thr
        int lin = it * 256 + t;
        int row = lin >> 4, u = lin & 15;
        int i = bid * PRB + row;
        int slot = s_slot[row];
        const float4* rp = (const float4*)(emb + (size_t)i * D);
        float4 a0 = rp[u * 2], a1 = rp[u * 2 + 1];
        float ssq = 0.f;
        ssq = fmaf(a0.x, a0.x, ssq); ssq = fmaf(a0.y, a0.y, ssq);
        ssq = fmaf(a0.z, a0.z, ssq); ssq = fmaf(a0.w, a0.w, ssq);
        ssq = fmaf(a1.x, a1.x, ssq); ssq = fmaf(a1.y, a1.y, ssq);
        ssq = fmaf(a1.z, a1.z, ssq); ssq = fmaf(a1.w, a1.w, ssq);
#pragma unroll
        for (int off = 8; off > 0; off >>= 1) ssq += __shfl_down(ssq, off, 16);
        // lane u==0 of each 16-group holds the total; no broadcast needed
        if (slot >= 0) {
            bf16x8 pk;
            pk[0] = f2bf(a0.x); pk[1] = f2bf(a0.y); pk[2] = f2bf(a0.z); pk[3] = f2bf(a0.w);
            pk[4] = f2bf(a1.x); pk[5] = f2bf(a1.y); pk[6] = f2bf(a1.z); pk[7] = f2bf(a1.w);
            *(bf16x8*)&ebf[(size_t)slot * D + u * 8] = pk;
            if (u == 0)
                pmeta[slot] = make_int4(labels[i], i, __float_as_int(ssq), 0);
        }
    }
}

// Load one j-tile's B fragment + column meta into NAMED registers
// (compile-time indices only — dynamic VGPR indexing demotes to scratch).
#define LOADTILE(B0, B1, B2, B3, MI, ML, MS, JT)                         \
    do {                                                                 \
        int jl_ = (JT) * TJ + w * 16 + c, cl_ = min(jl_, n - 1);         \
        const short* rp_ = ebf + (size_t)(base + cl_) * D;               \
        B0 = *(const bf16x8*)&rp_[q * 8];                                \
        B1 = *(const bf16x8*)&rp_[32 + q * 8];                           \
        B2 = *(const bf16x8*)&rp_[64 + q * 8];                           \
        B3 = *(const bf16x8*)&rp_[96 + q * 8];                           \
        int4 m_ = pmeta[base + cl_];                                     \
        MI = (jl_ < n) ? m_.y : -1; ML = m_.x; MS = __int_as_float(m_.z);\
    } while (0)

// Within a lane j is scanned ascending, so strict >/< keeps the smallest
// index on ties. Cross-lane reduces retain explicit tie-breaks.
#define STEP(B0, B1, B2, B3, MI, ML, MS)                                 \
    do {                                                                 \
        f32x4 acc = {0.f, 0.f, 0.f, 0.f};                                \
        acc = __builtin_amdgcn_mfma_f32_16x16x32_bf16(afr[0], B0, acc, 0, 0, 0); \
        acc = __builtin_amdgcn_mfma_f32_16x16x32_bf16(afr[1], B1, acc, 0, 0, 0); \
        acc = __builtin_amdgcn_mfma_f32_16x16x32_bf16(afr[2], B2, acc, 0, 0, 0); \
        acc = __builtin_amdgcn_mfma_f32_16x16x32_bf16(afr[3], B3, acc, 0, 0, 0); \
        if ((MI) >= 0) {                                                 \
            _Pragma("unroll")                                            \
            for (int r = 0; r < 4; ++r) {                                \
                float v = fmaf(-2.f, acc[r], (MS));                      \
                if ((ML) == li[r]) {                                     \
                    if ((MI) != gI[r] && v > vP[r]) { vP[r] = v; iP[r] = (MI); } \
                } else if (v < vN[r]) { vN[r] = v; iN[r] = (MI); }       \
            }                                                            \
        }                                                                \
    } while (0)

// triplet: EXACT Round-4 version (best measured config) — MFMA Gram + fused
// hardest-pos/neg selection, 4-deep register pipeline, plain-store partials.
__global__ __launch_bounds__(256, 2) void triplet_kernel(
        const short* __restrict__ ebf, const int4* __restrict__ pmeta,
        const int* __restrict__ counts,
        float* __restrict__ bsum, int* __restrict__ bcnt) {
    const int bid = blockIdx.x, t = threadIdx.x;
    const int s = bid & 15;              // subject -> XCD s%8 (blocks 16k+s pinned)
    const int stripe = bid >> 4;         // 0..31
    const int base = s * MAXN;
    const int n = min(counts[s], MAXN);
    const int lane = t & 63, w = t >> 6, c = lane & 15, q = lane >> 4;

    __shared__ float svP[TI][4]; __shared__ int siP[TI][4];
    __shared__ float svN[TI][4]; __shared__ int siN[TI][4];

    float blockSum = 0.f; int blockCnt = 0;

    for (int i0 = stripe * TI; i0 < n; i0 += NSTRIPE * TI) {
        const int nrows = min(TI, n - i0);

        bf16x8 afr[4];
        {
            const short* ap = ebf + (size_t)(base + i0 + min(c, nrows - 1)) * D;
#pragma unroll
            for (int st = 0; st < 4; ++st)
                afr[st] = *(const bf16x8*)&ap[st * 32 + q * 8];
        }
        int li[4], gI[4];
#pragma unroll
        for (int r = 0; r < 4; ++r) {
            int row = q * 4 + r;
            if (row < nrows) { int4 m = pmeta[base + i0 + row]; li[r] = m.x; gI[r] = m.y; }
            else             { li[r] = INT_MIN; gI[r] = -1; }
        }

        float vP[4], vN[4]; int iP[4], iN[4];
#pragma unroll
        for (int r = 0; r < 4; ++r) {
            vP[r] = -INFINITY; iP[r] = -1;
            vN[r] =  INFINITY; iN[r] = -1;
        }

        const int ntiles = (n + TJ - 1) / TJ;
        // ---- 4-deep pipeline, explicit named buffers, manual 4x unroll ----
        bf16x8 b00, b01, b02, b03, b10, b11, b12, b13;
        bf16x8 b20, b21, b22, b23, b30, b31, b32, b33;
        int mi0 = -1, ml0 = INT_MIN, mi1 = -1, ml1 = INT_MIN;
        int mi2 = -1, ml2 = INT_MIN, mi3 = -1, ml3 = INT_MIN;
        float ms0 = 0.f, ms1 = 0.f, ms2 = 0.f, ms3 = 0.f;
        if (0 < ntiles) LOADTILE(b00, b01, b02, b03, mi0, ml0, ms0, 0);
        if (1 < ntiles) LOADTILE(b10, b11, b12, b13, mi1, ml1, ms1, 1);
        if (2 < ntiles) LOADTILE(b20, b21, b22, b23, mi2, ml2, ms2, 2);
        if (3 < ntiles) LOADTILE(b30, b31, b32, b33, mi3, ml3, ms3, 3);

        for (int jt = 0; jt < ntiles; jt += 4) {
            {
                bf16x8 c0 = b00, c1 = b01, c2 = b02, c3 = b03;
                int cmi = mi0, cml = ml0; float cms = ms0;
                if (jt + 4 < ntiles) LOADTILE(b00, b01, b02, b03, mi0, ml0, ms0, jt + 4);
                STEP(c0, c1, c2, c3, cmi, cml, cms);
            }
            if (jt + 1 < ntiles) {
                bf16x8 c0 = b10, c1 = b11, c2 = b12, c3 = b13;
                int cmi = mi1, cml = ml1; float cms = ms1;
                if (jt + 5 < ntiles) LOADTILE(b10, b11, b12, b13, mi1, ml1, ms1, jt + 5);
                STEP(c0, c1, c2, c3, cmi, cml, cms);
            }
            if (jt + 2 < ntiles) {
                bf16x8 c0 = b20, c1 = b21, c2 = b22, c3 = b23;
                int cmi = mi2, cml = ml2; float cms = ms2;
                if (jt + 6 < ntiles) LOADTILE(b20, b21, b22, b23, mi2, ml2, ms2, jt + 6);
                STEP(c0, c1, c2, c3, cmi, cml, cms);
            }
            if (jt + 3 < ntiles) {
                bf16x8 c0 = b30, c1 = b31, c2 = b32, c3 = b33;
                int cmi = mi3, cml = ml3; float cms = ms3;
                if (jt + 7 < ntiles) LOADTILE(b30, b31, b32, b33, mi3, ml3, ms3, jt + 7);
                STEP(c0, c1, c2, c3, cmi, cml, cms);
            }
        }

        // reduce across the 16 col-lanes (tie-break: smallest original index)
#pragma unroll
        for (int off = 8; off > 0; off >>= 1) {
#pragma unroll
            for (int r = 0; r < 4; ++r) {
                float ov = __shfl_down(vP[r], off, 16);
                int   oi = __shfl_down(iP[r], off, 16);
                if (ov > vP[r] || (ov == vP[r] && (unsigned)oi < (unsigned)iP[r])) {
                    vP[r] = ov; iP[r] = oi;
                }
                float on = __shfl_down(vN[r], off, 16);
                int   oj = __shfl_down(iN[r], off, 16);
                if (on < vN[r] || (on == vN[r] && (unsigned)oj < (unsigned)iN[r])) {
                    vN[r] = on; iN[r] = oj;
                }
            }
        }
        if (c == 0) {
#pragma unroll
            for (int r = 0; r < 4; ++r) {
                int row = q * 4 + r;
                svP[row][w] = vP[r]; siP[row][w] = iP[r];
                svN[row][w] = vN[r]; siN[row][w] = iN[r];
            }
        }
        __syncthreads();

        // per-row combine + loss directly from d2:
        // d2 = (sq_j - 2 dot) + sq_i ; dap/dan = sqrt(max(d2,0))
        if (t < TI) {
            float bp = svP[t][0]; int ip = siP[t][0];
            float bn = svN[t][0]; int in_ = siN[t][0];
#pragma unroll
            for (int ww = 1; ww < 4; ++ww) {
                float o = svP[t][ww]; int oi = siP[t][ww];
                if (o > bp || (o == bp && (unsigned)oi < (unsigned)ip)) { bp = o; ip = oi; }
                float on = svN[t][ww]; int oj = siN[t][ww];
                if (on < bn || (on == bn && (unsigned)oj < (unsigned)in_)) { bn = on; in_ = oj; }
            }
            bool valid = (t < nrows) && (ip >= 0) && (in_ >= 0);
            float sqi = __int_as_float(pmeta[base + i0 + min(t, nrows - 1)].z);
            float per = 0.f;
            if (valid) {
                float dap = sqrtf(fmaxf(bp + sqi, 0.f));
                float dan = sqrtf(fmaxf(bn + sqi, 0.f));
                per = fmaxf(dap - dan + MARGIN, 0.f);
            }
            int vc = valid ? 1 : 0;
#pragma unroll
            for (int off = 8; off > 0; off >>= 1) {   // t<16 = lanes 0..15 of wave 0
                per += __shfl_down(per, off, 16);
                vc  += __shfl_down(vc,  off, 16);
            }
            if (t == 0) { blockSum += per; blockCnt += vc; }
        }
        if (i0 + NSTRIPE * TI < n) __syncthreads();   // barrier only if another stripe
    }

    // ---- epilogue: plain per-block partial store (distinct addresses;
    // written unconditionally every iteration -> no zeroing needed) ----
    if (t == 0) { bsum[bid] = blockSum; bcnt[bid] = blockCnt; }
}

// finalize: tree-sum the 512 partials (4 KB, L2-resident after the boundary
// flush) and write the mean. Dispatch boundary guarantees visibility.
__global__ __launch_bounds__(256) void finalize_kernel(
        const float* __restrict__ bsum, const int* __restrict__ bcnt,
        float* __restrict__ out) {
    __shared__ float ssum[4]; __shared__ int scnt[4];
    const int t = threadIdx.x;
    float s = 0.f; int c = 0;
#pragma unroll
    for (int i = t; i < NBLK; i += 256) { s += bsum[i]; c += bcnt[i]; }
#pragma unroll
    for (int off = 32; off > 0; off >>= 1) {
        s += __shfl_down(s, off, 64);
        c += __shfl_down(c, off, 64);
    }
    if ((t & 63) == 0) { ssum[t >> 6] = s; scnt[t >> 6] = c; }
    __syncthreads();
    if (t == 0) {
        float S = ssum[0] + ssum[1] + ssum[2] + ssum[3];
        int   C = scnt[0] + scnt[1] + scnt[2] + scnt[3];
        out[0] = (C > 0) ? (S / (float)C) : 0.0f;
    }
}

extern "C" void kernel_launch(void* const* d_in, const int* in_sizes, int n_in,
                              void* d_out, int out_size, void* d_ws, size_t ws_size,
                              hipStream_t stream) {
    const float* emb    = (const float*)d_in[0];
    const int*   labels = (const int*)d_in[1];
    const int*   sbj    = (const int*)d_in[2];
    float*       out    = (float*)d_out;
    int B = in_sizes[1];   // 8192

    // Workspace:
    //   [0,64)      int counts[16]
    //   [256,2304)  float bsum[NBLK]
    //   [2304,4352) int bcnt[NBLK]
    //   [4352, +NSUBJ*MAXN*16)       int4 pmeta (160 KB)
    //   [align256, +NSUBJ*MAXN*D*2)  short ebf (~2.62 MB)
    char*  ws        = (char*)d_ws;
    int*   counts    = (int*)ws;
    float* bsum      = (float*)(ws + 256);
    int*   bcnt      = (int*)(ws + 256 + NBLK * sizeof(float));
    size_t pmeta_off = (256 + 2 * (size_t)NBLK * sizeof(int) + 255) & ~(size_t)255;
    int4*  pmeta     = (int4*)(ws + pmeta_off);
    size_t ebf_off   = (pmeta_off + (size_t)NSUBJ * MAXN * sizeof(int4) + 255) & ~(size_t)255;
    short* ebf       = (short*)(ws + ebf_off);

    prep_kernel<<<B / PRB, 256, 0, stream>>>(emb, labels, sbj, counts,
                                             pmeta, ebf, B);
    triplet_kernel<<<NBLK, 256, 0, stream>>>(ebf, pmeta, counts, bsum, bcnt);
    finalize_kernel<<<1, 256, 0, stream>>>(bsum, bcnt, out);
}

// Round 7
// 93.038 us; speedup vs baseline: 1.2121x; 1.1022x over previous
//
#include <hip/hip_runtime.h>
#include <math.h>
#include <limits.h>

#define D 128
#define NSUBJ 16
#define MAXN 640        // bucket stride; groups ~512 +- 22 (~6 sigma safety)
#define MARGIN 0.8f
#define PRB 32          // rows per prep block
#define NPB 256         // prep blocks = 8192 / PRB
#define TI 16           // i-rows per triplet block (one MFMA row-tile)
#define TJ 64           // j-cols per tile (4 waves x 16)
#define NSTRIPE 32      // stripes per subject
#define NBLK (NSUBJ * NSTRIPE)   // 512 blocks = 2/CU

typedef __attribute__((ext_vector_type(8))) short bf16x8;
typedef __attribute__((ext_vector_type(4))) float f32x4;

static __device__ __forceinline__ short f2bf(float f) {
    union { float f; unsigned u; } v; v.f = f;
    unsigned r = v.u + 0x7FFF + ((v.u >> 16) & 1);   // RNE
    return (short)(r >> 16);
}

// ---------------------------------------------------------------------------
// P1: per-block subject histogram (LDS atomics only). Exactly R4's version.
// ---------------------------------------------------------------------------
__global__ __launch_bounds__(64) void hist_kernel(const int* __restrict__ sbj,
                                                  int* __restrict__ hist) {
    __shared__ int s_cnt[NSUBJ];
    const int t = threadIdx.x, bid = blockIdx.x;
    if (t < NSUBJ) s_cnt[t] = 0;
    __syncthreads();
    if (t < PRB) atomicAdd(&s_cnt[sbj[bid * PRB + t]], 1);
    __syncthreads();
    if (t < NSUBJ) hist[bid * NSUBJ + t] = s_cnt[t];
}

// ---------------------------------------------------------------------------
// P2: scan fused into prep (R4 version) + zeroing of the 512 done-flags
// (workspace is poison-filled each iteration; flags must start at 0).
// ---------------------------------------------------------------------------
__global__ __launch_bounds__(256) void prep_kernel(
        const float* __restrict__ emb, const int* __restrict__ labels,
        const int* __restrict__ sbj, const int* __restrict__ hist,
        int* __restrict__ counts, int* __restrict__ bcnt,
        int4* __restrict__ pmeta, short* __restrict__ ebf, int B) {
    __shared__ int s_cnt[NSUBJ], s_base[NSUBJ], s_slot[PRB];
    const int t = threadIdx.x, bid = blockIdx.x;
    if (t < 2) bcnt[bid * 2 + t] = 0;    // flag init (256 blocks x 2 = 512)
    if (t < NSUBJ) { s_cnt[t] = 0; s_base[t] = 0; }
    __syncthreads();
    // exclusive scan over preceding blocks: thread t covers subject t&15,
    // block segment [(t>>4)*16, +16) clipped to [0, bid)
    {
        const int ss = t & 15, seg0 = (t >> 4) * 16;
        int part = 0;
        const int hi = min(bid, seg0 + 16);
        for (int b = seg0; b < hi; ++b) part += hist[b * NSUBJ + ss];
        if (part) atomicAdd(&s_base[ss], part);
    }
    int s = 0, mypos = 0;
    if (t < PRB) { s = sbj[bid * PRB + t]; mypos = atomicAdd(&s_cnt[s], 1); }
    __syncthreads();
    if (t < PRB) {
        int pos = s_base[s] + mypos;
        s_slot[t] = (pos < MAXN) ? (s * MAXN + pos) : -1;   // never fires at 6 sigma
    }
    if (bid == NPB - 1 && t < NSUBJ)
        counts[t] = s_base[t] + s_cnt[t];                   // totals for triplet
    __syncthreads();
#pragma unroll
    for (int it = 0; it < (PRB * 16) / 256; ++it) {         // 2 iters: 16 rows x 16 thr
        int lin = it * 256 + t;
        int row = lin >> 4, u = lin & 15;
        int i = bid * PRB + row;
        int slot = s_slot[row];
        const float4* rp = (const float4*)(emb + (size_t)i * D);
        float4 a0 = rp[u * 2], a1 = rp[u * 2 + 1];
        float ssq = 0.f;
        ssq = fmaf(a0.x, a0.x, ssq); ssq = fmaf(a0.y, a0.y, ssq);
        ssq = fmaf(a0.z, a0.z, ssq); ssq = fmaf(a0.w, a0.w, ssq);
        ssq = fmaf(a1.x, a1.x, ssq); ssq = fmaf(a1.y, a1.y, ssq);
        ssq = fmaf(a1.z, a1.z, ssq); ssq = fmaf(a1.w, a1.w, ssq);
#pragma unroll
        for (int off = 8; off > 0; off >>= 1) ssq += __shfl_down(ssq, off, 16);
        // lane u==0 of each 16-group holds the total; no broadcast needed
        if (slot >= 0) {
            bf16x8 pk;
            pk[0] = f2bf(a0.x); pk[1] = f2bf(a0.y); pk[2] = f2bf(a0.z); pk[3] = f2bf(a0.w);
            pk[4] = f2bf(a1.x); pk[5] = f2bf(a1.y); pk[6] = f2bf(a1.z); pk[7] = f2bf(a1.w);
            *(bf16x8*)&ebf[(size_t)slot * D + u * 8] = pk;
            if (u == 0)
                pmeta[slot] = make_int4(labels[i], i, __float_as_int(ssq), 0);
        }
    }
}

// Load one j-tile's B fragment + column meta into NAMED registers
// (compile-time indices only — dynamic VGPR indexing demotes to scratch).
#define LOADTILE(B0, B1, B2, B3, MI, ML, MS, JT)                         \
    do {                                                                 \
        int jl_ = (JT) * TJ + w * 16 + c, cl_ = min(jl_, n - 1);         \
        const short* rp_ = ebf + (size_t)(base + cl_) * D;               \
        B0 = *(const bf16x8*)&rp_[q * 8];                                \
        B1 = *(const bf16x8*)&rp_[32 + q * 8];                           \
        B2 = *(const bf16x8*)&rp_[64 + q * 8];                           \
        B3 = *(const bf16x8*)&rp_[96 + q * 8];                           \
        int4 m_ = pmeta[base + cl_];                                     \
        MI = (jl_ < n) ? m_.y : -1; ML = m_.x; MS = __int_as_float(m_.z);\
    } while (0)

// Within a lane j is scanned ascending, so strict >/< keeps the smallest
// index on ties. Cross-lane reduces retain explicit tie-breaks.
#define STEP(B0, B1, B2, B3, MI, ML, MS)                                 \
    do {                                                                 \
        f32x4 acc = {0.f, 0.f, 0.f, 0.f};                                \
        acc = __builtin_amdgcn_mfma_f32_16x16x32_bf16(afr[0], B0, acc, 0, 0, 0); \
        acc = __builtin_amdgcn_mfma_f32_16x16x32_bf16(afr[1], B1, acc, 0, 0, 0); \
        acc = __builtin_amdgcn_mfma_f32_16x16x32_bf16(afr[2], B2, acc, 0, 0, 0); \
        acc = __builtin_amdgcn_mfma_f32_16x16x32_bf16(afr[3], B3, acc, 0, 0, 0); \
        if ((MI) >= 0) {                                                 \
            _Pragma("unroll")                                            \
            for (int r = 0; r < 4; ++r) {                                \
                float v = fmaf(-2.f, acc[r], (MS));                      \
                if ((ML) == li[r]) {                                     \
                    if ((MI) != gI[r] && v > vP[r]) { vP[r] = v; iP[r] = (MI); } \
                } else if (v < vN[r]) { vN[r] = v; iN[r] = (MI); }       \
            }                                                            \
        }                                                                \
    } while (0)

// triplet: EXACT R4 compute; epilogue publishes {sum, cnt+1} via DEVICE-SCOPE
// RELAXED atomic stores (straight to coherence point — no fence, no L2
// writeback, no ticket serialization), ordered by s_waitcnt vmcnt(0) (waits
// only this wave's own stores). Block 0 polls the 512 flags and writes the
// mean — fuses the finalize dispatch away (-1 launch, -1 boundary drain).
// No deadlock possible: no block ever waits on block 0.
__global__ __launch_bounds__(256, 2) void triplet_kernel(
        const short* __restrict__ ebf, const int4* __restrict__ pmeta,
        const int* __restrict__ counts,
        float* __restrict__ bsum, int* __restrict__ bcnt,
        float* __restrict__ out) {
    const int bid = blockIdx.x, t = threadIdx.x;
    const int s = bid & 15;              // subject -> XCD s%8 (blocks 16k+s pinned)
    const int stripe = bid >> 4;         // 0..31
    const int base = s * MAXN;
    const int n = min(counts[s], MAXN);
    const int lane = t & 63, w = t >> 6, c = lane & 15, q = lane >> 4;

    __shared__ float svP[TI][4]; __shared__ int siP[TI][4];
    __shared__ float svN[TI][4]; __shared__ int siN[TI][4];
    __shared__ float fsum[4]; __shared__ int fcnt[4];

    float blockSum = 0.f; int blockCnt = 0;

    for (int i0 = stripe * TI; i0 < n; i0 += NSTRIPE * TI) {
        const int nrows = min(TI, n - i0);

        bf16x8 afr[4];
        {
            const short* ap = ebf + (size_t)(base + i0 + min(c, nrows - 1)) * D;
#pragma unroll
            for (int st = 0; st < 4; ++st)
                afr[st] = *(const bf16x8*)&ap[st * 32 + q * 8];
        }
        int li[4], gI[4];
#pragma unroll
        for (int r = 0; r < 4; ++r) {
            int row = q * 4 + r;
            if (row < nrows) { int4 m = pmeta[base + i0 + row]; li[r] = m.x; gI[r] = m.y; }
            else             { li[r] = INT_MIN; gI[r] = -1; }
        }

        float vP[4], vN[4]; int iP[4], iN[4];
#pragma unroll
        for (int r = 0; r < 4; ++r) {
            vP[r] = -INFINITY; iP[r] = -1;
            vN[r] =  INFINITY; iN[r] = -1;
        }

        const int ntiles = (n + TJ - 1) / TJ;
        // ---- 4-deep pipeline, explicit named buffers, manual 4x unroll ----
        bf16x8 b00, b01, b02, b03, b10, b11, b12, b13;
        bf16x8 b20, b21, b22, b23, b30, b31, b32, b33;
        int mi0 = -1, ml0 = INT_MIN, mi1 = -1, ml1 = INT_MIN;
        int mi2 = -1, ml2 = INT_MIN, mi3 = -1, ml3 = INT_MIN;
        float ms0 = 0.f, ms1 = 0.f, ms2 = 0.f, ms3 = 0.f;
        if (0 < ntiles) LOADTILE(b00, b01, b02, b03, mi0, ml0, ms0, 0);
        if (1 < ntiles) LOADTILE(b10, b11, b12, b13, mi1, ml1, ms1, 1);
        if (2 < ntiles) LOADTILE(b20, b21, b22, b23, mi2, ml2, ms2, 2);
        if (3 < ntiles) LOADTILE(b30, b31, b32, b33, mi3, ml3, ms3, 3);

        for (int jt = 0; jt < ntiles; jt += 4) {
            {
                bf16x8 c0 = b00, c1 = b01, c2 = b02, c3 = b03;
                int cmi = mi0, cml = ml0; float cms = ms0;
                if (jt + 4 < ntiles) LOADTILE(b00, b01, b02, b03, mi0, ml0, ms0, jt + 4);
                STEP(c0, c1, c2, c3, cmi, cml, cms);
            }
            if (jt + 1 < ntiles) {
                bf16x8 c0 = b10, c1 = b11, c2 = b12, c3 = b13;
                int cmi = mi1, cml = ml1; float cms = ms1;
                if (jt + 5 < ntiles) LOADTILE(b10, b11, b12, b13, mi1, ml1, ms1, jt + 5);
                STEP(c0, c1, c2, c3, cmi, cml, cms);
            }
            if (jt + 2 < ntiles) {
                bf16x8 c0 = b20, c1 = b21, c2 = b22, c3 = b23;
                int cmi = mi2, cml = ml2; float cms = ms2;
                if (jt + 6 < ntiles) LOADTILE(b20, b21, b22, b23, mi2, ml2, ms2, jt + 6);
                STEP(c0, c1, c2, c3, cmi, cml, cms);
            }
            if (jt + 3 < ntiles) {
                bf16x8 c0 = b30, c1 = b31, c2 = b32, c3 = b33;
                int cmi = mi3, cml = ml3; float cms = ms3;
                if (jt + 7 < ntiles) LOADTILE(b30, b31, b32, b33, mi3, ml3, ms3, jt + 7);
                STEP(c0, c1, c2, c3, cmi, cml, cms);
            }
        }

        // reduce across the 16 col-lanes (tie-break: smallest original index)
#pragma unroll
        for (int off = 8; off > 0; off >>= 1) {
#pragma unroll
            for (int r = 0; r < 4; ++r) {
                float ov = __shfl_down(vP[r], off, 16);
                int   oi = __shfl_down(iP[r], off, 16);
                if (ov > vP[r] || (ov == vP[r] && (unsigned)oi < (unsigned)iP[r])) {
                    vP[r] = ov; iP[r] = oi;
                }
                float on = __shfl_down(vN[r], off, 16);
                int   oj = __shfl_down(iN[r], off, 16);
                if (on < vN[r] || (on == vN[r] && (unsigned)oj < (unsigned)iN[r])) {
                    vN[r] = on; iN[r] = oj;
                }
            }
        }
        if (c == 0) {
#pragma unroll
            for (int r = 0; r < 4; ++r) {
                int row = q * 4 + r;
                svP[row][w] = vP[r]; siP[row][w] = iP[r];
                svN[row][w] = vN[r]; siN[row][w] = iN[r];
            }
        }
        __syncthreads();

        // per-row combine + loss directly from d2:
        // d2 = (sq_j - 2 dot) + sq_i ; dap/dan = sqrt(max(d2,0))
        if (t < TI) {
            float bp = svP[t][0]; int ip = siP[t][0];
            float bn = svN[t][0]; int in_ = siN[t][0];
#pragma unroll
            for (int ww = 1; ww < 4; ++ww) {
                float o = svP[t][ww]; int oi = siP[t][ww];
                if (o > bp || (o == bp && (unsigned)oi < (unsigned)ip)) { bp = o; ip = oi; }
                float on = svN[t][ww]; int oj = siN[t][ww];
                if (on < bn || (on == bn && (unsigned)oj < (unsigned)in_)) { bn = on; in_ = oj; }
            }
            bool valid = (t < nrows) && (ip >= 0) && (in_ >= 0);
            float sqi = __int_as_float(pmeta[base + i0 + min(t, nrows - 1)].z);
            float per = 0.f;
            if (valid) {
                float dap = sqrtf(fmaxf(bp + sqi, 0.f));
                float dan = sqrtf(fmaxf(bn + sqi, 0.f));
                per = fmaxf(dap - dan + MARGIN, 0.f);
            }
            int vc = valid ? 1 : 0;
#pragma unroll
            for (int off = 8; off > 0; off >>= 1) {   // t<16 = lanes 0..15 of wave 0
                per += __shfl_down(per, off, 16);
                vc  += __shfl_down(vc,  off, 16);
            }
            if (t == 0) { blockSum += per; blockCnt += vc; }
        }
        if (i0 + NSTRIPE * TI < n) __syncthreads();   // barrier only if another stripe
    }

    // ---- publish partial: device-scope relaxed stores, own-store waitcnt
    // orders sum before flag; flag = cnt+1 (always nonzero) ----
    if (t == 0) {
        __hip_atomic_store(&bsum[bid], blockSum,
                           __ATOMIC_RELAXED, __HIP_MEMORY_SCOPE_AGENT);
        asm volatile("s_waitcnt vmcnt(0)" ::: "memory");
        __hip_atomic_store(&bcnt[bid], blockCnt + 1,
                           __ATOMIC_RELAXED, __HIP_MEMORY_SCOPE_AGENT);
    }

    // ---- fused finalize: block 0 polls all 512 flags, sums, writes mean ----
    if (bid == 0) {
        float s2 = 0.f; int c2 = 0;
        for (int i = t; i < NBLK; i += 256) {
            int v;
            while ((v = __hip_atomic_load(&bcnt[i], __ATOMIC_RELAXED,
                                          __HIP_MEMORY_SCOPE_AGENT)) == 0)
                __builtin_amdgcn_s_sleep(8);
            c2 += v - 1;
            s2 += __hip_atomic_load(&bsum[i], __ATOMIC_RELAXED,
                                    __HIP_MEMORY_SCOPE_AGENT);
        }
#pragma unroll
        for (int off = 32; off > 0; off >>= 1) {
            s2 += __shfl_down(s2, off, 64);
            c2 += __shfl_down(c2, off, 64);
        }
        if ((t & 63) == 0) { fsum[t >> 6] = s2; fcnt[t >> 6] = c2; }
        __syncthreads();
        if (t == 0) {
            float S = fsum[0] + fsum[1] + fsum[2] + fsum[3];
            int   C = fcnt[0] + fcnt[1] + fcnt[2] + fcnt[3];
            out[0] = (C > 0) ? (S / (float)C) : 0.0f;
        }
    }
}

extern "C" void kernel_launch(void* const* d_in, const int* in_sizes, int n_in,
                              void* d_out, int out_size, void* d_ws, size_t ws_size,
                              hipStream_t stream) {
    const float* emb    = (const float*)d_in[0];
    const int*   labels = (const int*)d_in[1];
    const int*   sbj    = (const int*)d_in[2];
    float*       out    = (float*)d_out;
    int B = in_sizes[1];   // 8192

    // Workspace:
    //   [0,64)      int counts[16]
    //   [256,2304)  float bsum[NBLK]
    //   [2304,4352) int bcnt[NBLK]   (flags; zeroed by prep)
    //   [4352, +NPB*NSUBJ*4)         int hist[NPB][NSUBJ] (16 KB)
    //   [align256, +NSUBJ*MAXN*16)   int4 pmeta (160 KB)
    //   [align256, +NSUBJ*MAXN*D*2)  short ebf (~2.62 MB)
    char*  ws        = (char*)d_ws;
    int*   counts    = (int*)ws;
    float* bsum      = (float*)(ws + 256);
    int*   bcnt      = (int*)(ws + 256 + NBLK * sizeof(float));
    int*   hist      = (int*)(ws + 256 + 2 * NBLK * sizeof(int));
    size_t pmeta_off = (256 + 2 * (size_t)NBLK * sizeof(int)
                        + (size_t)NPB * NSUBJ * sizeof(int) + 255) & ~(size_t)255;
    int4*  pmeta     = (int4*)(ws + pmeta_off);
    size_t ebf_off   = (pmeta_off + (size_t)NSUBJ * MAXN * sizeof(int4) + 255) & ~(size_t)255;
    short* ebf       = (short*)(ws + ebf_off);

    hist_kernel<<<B / PRB, 64, 0, stream>>>(sbj, hist);
    prep_kernel<<<B / PRB, 256, 0, stream>>>(emb, labels, sbj, hist, counts,
                                             bcnt, pmeta, ebf, B);
    triplet_kernel<<<NBLK, 256, 0, stream>>>(ebf, pmeta, counts, bsum, bcnt, out);
}

// Round 8
// 86.271 us; speedup vs baseline: 1.3072x; 1.0784x over previous
//
#include <hip/hip_runtime.h>
#include <math.h>
#include <limits.h>

#define D 128
#define NSUBJ 16
#define MAXN 640        // bucket stride; groups ~512 +- 22 (~6 sigma safety)
#define MARGIN 0.8f
#define PRB 32          // rows per prep block
#define NPB 256         // prep blocks = 8192 / PRB
#define TI 16           // i-rows per triplet block (one MFMA row-tile)
#define TJ 64           // j-cols per tile (4 waves x 16)
#define NSTRIPE 32      // stripes per subject
#define NBLK (NSUBJ * NSTRIPE)   // 512 blocks = 2/CU

typedef __attribute__((ext_vector_type(8))) short bf16x8;
typedef __attribute__((ext_vector_type(4))) float f32x4;

static __device__ __forceinline__ short f2bf(float f) {
    union { float f; unsigned u; } v; v.f = f;
    unsigned r = v.u + 0x7FFF + ((v.u >> 16) & 1);   // RNE
    return (short)(r >> 16);
}

// async global->LDS, 16B per lane: LDS dest = uniform base + lane*16 (HW),
// global src = fully per-lane address (pre-swizzled there if needed).
static __device__ __forceinline__ void gload_lds16(const void* g, void* l) {
    __builtin_amdgcn_global_load_lds(
        (const __attribute__((address_space(1))) void*)g,
        (__attribute__((address_space(3))) void*)l, 16, 0, 0);
}

// ---------------------------------------------------------------------------
// P1: per-block subject histogram (LDS atomics only). R4 version.
// ---------------------------------------------------------------------------
__global__ __launch_bounds__(64) void hist_kernel(const int* __restrict__ sbj,
                                                  int* __restrict__ hist) {
    __shared__ int s_cnt[NSUBJ];
    const int t = threadIdx.x, bid = blockIdx.x;
    if (t < NSUBJ) s_cnt[t] = 0;
    __syncthreads();
    if (t < PRB) atomicAdd(&s_cnt[sbj[bid * PRB + t]], 1);
    __syncthreads();
    if (t < NSUBJ) hist[bid * NSUBJ + t] = s_cnt[t];
}

// ---------------------------------------------------------------------------
// P2: scan fused into prep. R4 version (measured best).
// ---------------------------------------------------------------------------
__global__ __launch_bounds__(256) void prep_kernel(
        const float* __restrict__ emb, const int* __restrict__ labels,
        const int* __restrict__ sbj, const int* __restrict__ hist,
        int* __restrict__ counts,
        int4* __restrict__ pmeta, short* __restrict__ ebf, int B) {
    __shared__ int s_cnt[NSUBJ], s_base[NSUBJ], s_slot[PRB];
    const int t = threadIdx.x, bid = blockIdx.x;
    if (t < NSUBJ) { s_cnt[t] = 0; s_base[t] = 0; }
    __syncthreads();
    {
        const int ss = t & 15, seg0 = (t >> 4) * 16;
        int part = 0;
        const int hi = min(bid, seg0 + 16);
        for (int b = seg0; b < hi; ++b) part += hist[b * NSUBJ + ss];
        if (part) atomicAdd(&s_base[ss], part);
    }
    int s = 0, mypos = 0;
    if (t < PRB) { s = sbj[bid * PRB + t]; mypos = atomicAdd(&s_cnt[s], 1); }
    __syncthreads();
    if (t < PRB) {
        int pos = s_base[s] + mypos;
        s_slot[t] = (pos < MAXN) ? (s * MAXN + pos) : -1;   // never fires at 6 sigma
    }
    if (bid == NPB - 1 && t < NSUBJ)
        counts[t] = s_base[t] + s_cnt[t];                   // totals for triplet
    __syncthreads();
#pragma unroll
    for (int it = 0; it < (PRB * 16) / 256; ++it) {         // 2 iters: 16 rows x 16 thr
        int lin = it * 256 + t;
        int row = lin >> 4, u = lin & 15;
        int i = bid * PRB + row;
        int slot = s_slot[row];
        const float4* rp = (const float4*)(emb + (size_t)i * D);
        float4 a0 = rp[u * 2], a1 = rp[u * 2 + 1];
        float ssq = 0.f;
        ssq = fmaf(a0.x, a0.x, ssq); ssq = fmaf(a0.y, a0.y, ssq);
        ssq = fmaf(a0.z, a0.z, ssq); ssq = fmaf(a0.w, a0.w, ssq);
        ssq = fmaf(a1.x, a1.x, ssq); ssq = fmaf(a1.y, a1.y, ssq);
        ssq = fmaf(a1.z, a1.z, ssq); ssq = fmaf(a1.w, a1.w, ssq);
#pragma unroll
        for (int off = 8; off > 0; off >>= 1) ssq += __shfl_down(ssq, off, 16);
        if (slot >= 0) {
            bf16x8 pk;
            pk[0] = f2bf(a0.x); pk[1] = f2bf(a0.y); pk[2] = f2bf(a0.z); pk[3] = f2bf(a0.w);
            pk[4] = f2bf(a1.x); pk[5] = f2bf(a1.y); pk[6] = f2bf(a1.z); pk[7] = f2bf(a1.w);
            *(bf16x8*)&ebf[(size_t)slot * D + u * 8] = pk;
            if (u == 0)
                pmeta[slot] = make_int4(labels[i], i, __float_as_int(ssq), 0);
        }
    }
}

// Stage one 64-row j-tile (16 KB, CONTIGUOUS in ebf) into LDS buffer BUF.
// 4 gload_lds per wave (16 per block). LDS dest linear; global SOURCE carries
// the XOR swizzle (byte ^= (row&7)<<4, bits 4-6 only -> stays in-row), so the
// swizzled ds_read below returns the original bytes (both-sides involution).
#define STAGE(BUF, JT)                                                    \
    do {                                                                  \
        const char* ts_ = (const char*)ebf + ((size_t)(base + (JT) * TJ)) * 256; \
        _Pragma("unroll")                                                 \
        for (int ii_ = 0; ii_ < 4; ++ii_) {                               \
            int lin_ = ((w * 4 + ii_) * 64 + lane) * 16;                  \
            int row_ = lin_ >> 8;                                         \
            gload_lds16(ts_ + (lin_ ^ ((row_ & 7) << 4)),                 \
                        ldsB + (BUF) * (TJ * 256) + (w * 4 + ii_) * 1024);\
        }                                                                 \
    } while (0)

// triplet: LDS-staged B-tiles via global_load_lds + counted vmcnt(4) dbuf
// (never drain to 0 mid-loop; raw s_barrier, NOT __syncthreads which drains
// vmcnt). Replaces 80 scattered 16B wave-loads per tile with 16 coalesced
// 1KB ones — attacks the latency stall (R1: 93% stall, MfmaUtil 0.9%).
// MFMA + selection arithmetic bit-identical to R4.
__global__ __launch_bounds__(256, 2) void triplet_kernel(
        const short* __restrict__ ebf, const int4* __restrict__ pmeta,
        const int* __restrict__ counts,
        float* __restrict__ bsum, int* __restrict__ bcnt) {
    const int bid = blockIdx.x, t = threadIdx.x;
    const int s = bid & 15;              // subject -> XCD s%8 (blocks 16k+s pinned)
    const int stripe = bid >> 4;         // 0..31
    const int base = s * MAXN;
    const int n = min(counts[s], MAXN);
    const int lane = t & 63, w = t >> 6, c = lane & 15, q = lane >> 4;

    __shared__ char ldsB[2 * TJ * 256];  // 32 KB: double-buffered B-tile (swizzled)
    __shared__ char ldsM[MAXN * 16];     // 10 KB: whole panel meta (linear)
    __shared__ float svP[TI][4]; __shared__ int siP[TI][4];
    __shared__ float svN[TI][4]; __shared__ int siN[TI][4];

    const int ntiles = (n + TJ - 1) / TJ;

    // ---- stage entire panel meta once (oldest in vmcnt queue; drained by the
    // first vmcnt(4) wait together with tile 0) ----
    for (int r = w; r < ntiles; r += 4)
        gload_lds16((const char*)(pmeta + base + r * 64) + lane * 16,
                    ldsM + r * 1024);

    float blockSum = 0.f; int blockCnt = 0;

    for (int i0 = stripe * TI; i0 < n; i0 += NSTRIPE * TI) {
        const int nrows = min(TI, n - i0);

        // A fragments (row = i0 + c) + i-row meta, from global (prologue-only)
        bf16x8 afr[4];
        {
            const short* ap = ebf + (size_t)(base + i0 + min(c, nrows - 1)) * D;
#pragma unroll
            for (int st = 0; st < 4; ++st)
                afr[st] = *(const bf16x8*)&ap[st * 32 + q * 8];
        }
        int li[4], gI[4];
#pragma unroll
        for (int r = 0; r < 4; ++r) {
            int row = q * 4 + r;
            if (row < nrows) { int4 m = pmeta[base + i0 + row]; li[r] = m.x; gI[r] = m.y; }
            else             { li[r] = INT_MIN; gI[r] = -1; }
        }

        float vP[4], vN[4]; int iP[4], iN[4];
#pragma unroll
        for (int r = 0; r < 4; ++r) {
            vP[r] = -INFINITY; iP[r] = -1;
            vN[r] =  INFINITY; iN[r] = -1;
        }

        // ---- prologue: stage tiles 0,1 ----
        STAGE(0, 0);
        if (1 < ntiles) STAGE(1, 1);
        int cur = 0;

        for (int jt = 0; jt < ntiles; ++jt) {
            // wait own stages for tile jt (leave next tile's 4 in flight)
            if (jt + 1 < ntiles) asm volatile("s_waitcnt vmcnt(4)" ::: "memory");
            else                 asm volatile("s_waitcnt vmcnt(0)" ::: "memory");
            __builtin_amdgcn_sched_barrier(0);
            __builtin_amdgcn_s_barrier();          // all waves' stages landed
            __builtin_amdgcn_sched_barrier(0);

            {   // consume buf cur: swizzled ds_read + MFMA + fused select
                const char* bb = ldsB + cur * (TJ * 256);
                const int lr = w * 16 + c, swz = (lr & 7) << 4;
                bf16x8 f0 = *(const bf16x8*)(bb + lr * 256 + ((  0 + q * 16) ^ swz));
                bf16x8 f1 = *(const bf16x8*)(bb + lr * 256 + (( 64 + q * 16) ^ swz));
                bf16x8 f2 = *(const bf16x8*)(bb + lr * 256 + ((128 + q * 16) ^ swz));
                bf16x8 f3 = *(const bf16x8*)(bb + lr * 256 + ((192 + q * 16) ^ swz));
                const int jl = jt * TJ + lr;
                int4 m = *(const int4*)(ldsM + jl * 16);
                const int MI = (jl < n) ? m.y : -1;
                const int ML = m.x; const float MS = __int_as_float(m.z);

                f32x4 acc = {0.f, 0.f, 0.f, 0.f};
                acc = __builtin_amdgcn_mfma_f32_16x16x32_bf16(afr[0], f0, acc, 0, 0, 0);
                acc = __builtin_amdgcn_mfma_f32_16x16x32_bf16(afr[1], f1, acc, 0, 0, 0);
                acc = __builtin_amdgcn_mfma_f32_16x16x32_bf16(afr[2], f2, acc, 0, 0, 0);
                acc = __builtin_amdgcn_mfma_f32_16x16x32_bf16(afr[3], f3, acc, 0, 0, 0);
                if (MI >= 0) {
#pragma unroll
                    for (int r = 0; r < 4; ++r) {
                        float v = fmaf(-2.f, acc[r], MS);
                        if (ML == li[r]) {
                            if (MI != gI[r] && v > vP[r]) { vP[r] = v; iP[r] = MI; }
                        } else if (v < vN[r]) { vN[r] = v; iN[r] = MI; }
                    }
                }
            }

            __builtin_amdgcn_s_barrier();          // all waves done reading cur
            __builtin_amdgcn_sched_barrier(0);
            if (jt + 2 < ntiles) STAGE(cur, jt + 2);  // refill freed buffer
            cur ^= 1;
        }

        // reduce across the 16 col-lanes (tie-break: smallest original index)
#pragma unroll
        for (int off = 8; off > 0; off >>= 1) {
#pragma unroll
            for (int r = 0; r < 4; ++r) {
                float ov = __shfl_down(vP[r], off, 16);
                int   oi = __shfl_down(iP[r], off, 16);
                if (ov > vP[r] || (ov == vP[r] && (unsigned)oi < (unsigned)iP[r])) {
                    vP[r] = ov; iP[r] = oi;
                }
                float on = __shfl_down(vN[r], off, 16);
                int   oj = __shfl_down(iN[r], off, 16);
                if (on < vN[r] || (on == vN[r] && (unsigned)oj < (unsigned)iN[r])) {
                    vN[r] = on; iN[r] = oj;
                }
            }
        }
        if (c == 0) {
#pragma unroll
            for (int r = 0; r < 4; ++r) {
                int row = q * 4 + r;
                svP[row][w] = vP[r]; siP[row][w] = iP[r];
                svN[row][w] = vN[r]; siN[row][w] = iN[r];
            }
        }
        __syncthreads();

        // per-row combine + loss directly from d2:
        // d2 = (sq_j - 2 dot) + sq_i ; dap/dan = sqrt(max(d2,0))
        if (t < TI) {
            float bp = svP[t][0]; int ip = siP[t][0];
            float bn = svN[t][0]; int in_ = siN[t][0];
#pragma unroll
            for (int ww = 1; ww < 4; ++ww) {
                float o = svP[t][ww]; int oi = siP[t][ww];
                if (o > bp || (o == bp && (unsigned)oi < (unsigned)ip)) { bp = o; ip = oi; }
                float on = svN[t][ww]; int oj = siN[t][ww];
                if (on < bn || (on == bn && (unsigned)oj < (unsigned)in_)) { bn = on; in_ = oj; }
            }
            bool valid = (t < nrows) && (ip >= 0) && (in_ >= 0);
            float sqi = __int_as_float(
                ((const int4*)(ldsM + (i0 + min(t, nrows - 1)) * 16))->z);
            float per = 0.f;
            if (valid) {
                float dap = sqrtf(fmaxf(bp + sqi, 0.f));
                float dan = sqrtf(fmaxf(bn + sqi, 0.f));
                per = fmaxf(dap - dan + MARGIN, 0.f);
            }
            int vc = valid ? 1 : 0;
#pragma unroll
            for (int off = 8; off > 0; off >>= 1) {   // t<16 = lanes 0..15 of wave 0
                per += __shfl_down(per, off, 16);
                vc  += __shfl_down(vc,  off, 16);
            }
            if (t == 0) { blockSum += per; blockCnt += vc; }
        }
        if (i0 + NSTRIPE * TI < n) __syncthreads();   // barrier only if another stripe
    }

    // ---- epilogue: plain per-block partial store (no atomics, no fence) ----
    if (t == 0) { bsum[bid] = blockSum; bcnt[bid] = blockCnt; }
}

// finalize: tree-sum the 512 partials (4 KB) and write the mean. R4 version.
__global__ __launch_bounds__(256) void finalize_kernel(
        const float* __restrict__ bsum, const int* __restrict__ bcnt,
        float* __restrict__ out) {
    __shared__ float ssum[4]; __shared__ int scnt[4];
    const int t = threadIdx.x;
    float s = 0.f; int c = 0;
#pragma unroll
    for (int i = t; i < NBLK; i += 256) { s += bsum[i]; c += bcnt[i]; }
#pragma unroll
    for (int off = 32; off > 0; off >>= 1) {
        s += __shfl_down(s, off, 64);
        c += __shfl_down(c, off, 64);
    }
    if ((t & 63) == 0) { ssum[t >> 6] = s; scnt[t >> 6] = c; }
    __syncthreads();
    if (t == 0) {
        float S = ssum[0] + ssum[1] + ssum[2] + ssum[3];
        int   C = scnt[0] + scnt[1] + scnt[2] + scnt[3];
        out[0] = (C > 0) ? (S / (float)C) : 0.0f;
    }
}

extern "C" void kernel_launch(void* const* d_in, const int* in_sizes, int n_in,
                              void* d_out, int out_size, void* d_ws, size_t ws_size,
                              hipStream_t stream) {
    const float* emb    = (const float*)d_in[0];
    const int*   labels = (const int*)d_in[1];
    const int*   sbj    = (const int*)d_in[2];
    float*       out    = (float*)d_out;
    int B = in_sizes[1];   // 8192

    // Workspace:
    //   [0,64)      int counts[16]
    //   [256,2304)  float bsum[NBLK]
    //   [2304,4352) int bcnt[NBLK]
    //   [4352, +NPB*NSUBJ*4)         int hist[NPB][NSUBJ] (16 KB)
    //   [align256, +NSUBJ*MAXN*16)   int4 pmeta (160 KB)
    //   [align256, +NSUBJ*MAXN*D*2)  short ebf (~2.62 MB)
    char*  ws        = (char*)d_ws;
    int*   counts    = (int*)ws;
    float* bsum      = (float*)(ws + 256);
    int*   bcnt      = (int*)(ws + 256 + NBLK * sizeof(float));
    int*   hist      = (int*)(ws + 256 + 2 * NBLK * sizeof(int));
    size_t pmeta_off = (256 + 2 * (size_t)NBLK * sizeof(int)
                        + (size_t)NPB * NSUBJ * sizeof(int) + 255) & ~(size_t)255;
    int4*  pmeta     = (int4*)(ws + pmeta_off);
    size_t ebf_off   = (pmeta_off + (size_t)NSUBJ * MAXN * sizeof(int4) + 255) & ~(size_t)255;
    short* ebf       = (short*)(ws + ebf_off);

    hist_kernel<<<B / PRB, 64, 0, stream>>>(sbj, hist);
    prep_kernel<<<B / PRB, 256, 0, stream>>>(emb, labels, sbj, hist, counts,
                                             pmeta, ebf, B);
    triplet_kernel<<<NBLK, 256, 0, stream>>>(ebf, pmeta, counts, bsum, bcnt);
    finalize_kernel<<<1, 256, 0, stream>>>(bsum, bcnt, out);
}